// Round 1
// baseline (96.275 us; speedup 1.0000x reference)
//
#include <hip/hip_runtime.h>
#include <hip/hip_bf16.h>

// Shapes (fixed by reference): SEQ=512, BATCH=64, DIM=512, MAXLEN=512, E=655360
// out[b][u][s] = edge(b,u,s) ? exp(scale[s,b,u]-mx)/ (T_e + 1e-10*(T-T_e)) : 0
// scale[s,b,m] = sum_d M[s,b,d] * W[m,d]

#define SEQ 512
#define BATCH 64
#define DIM 512
#define MAXLEN 512

typedef __attribute__((ext_vector_type(8))) __bf16 bf16x8;
typedef __attribute__((ext_vector_type(8))) unsigned short u16x8;
typedef __attribute__((ext_vector_type(4))) float f32x4;

__device__ __forceinline__ unsigned short f2bf(float f) {
    unsigned int u = __builtin_bit_cast(unsigned int, f);
    u += 0x7FFFu + ((u >> 16) & 1u);   // RNE
    return (unsigned short)(u >> 16);
}

__device__ __forceinline__ bf16x8 lds_frag(const unsigned short* p) {
    u16x8 r = *reinterpret_cast<const u16x8*>(p);
    return __builtin_bit_cast(bf16x8, r);
}

// ---------------- edge bitmap scatter ----------------
__global__ __launch_bounds__(256) void edge_scatter(const int* __restrict__ eb,
                                                    const int* __restrict__ eu,
                                                    const int* __restrict__ ev,
                                                    unsigned int* __restrict__ bits,
                                                    int E) {
    int i = blockIdx.x * 256 + threadIdx.x;
    if (i < E) {
        int b = eb[i], u = eu[i], v = ev[i];
        atomicOr(&bits[(b * MAXLEN + u) * 16 + (v >> 5)], 1u << (v & 31));
    }
}

// ---------------- GEMM: scale[b][m][s] = sum_d W[m,d]*M[s,b,d] ----------------
// grid (s_tile=4, m_tile=4, b=64), block 256 (4 waves, 2x2), tile 128x128, BK=64
#define LDP 72  // lds pitch (bf16 elems): 144B rows -> 16B aligned, 2-way bank alias (free)

__global__ __launch_bounds__(256) void gemm_scale(const float* __restrict__ Mg,
                                                  const float* __restrict__ Wg,
                                                  float* __restrict__ out) {
    __shared__ unsigned short Wt[128 * LDP];
    __shared__ unsigned short Mt[128 * LDP];

    const int b  = blockIdx.z;
    const int m0 = blockIdx.y * 128;
    const int s0 = blockIdx.x * 128;
    const int t  = threadIdx.x;
    const int lane = t & 63;
    const int wv = t >> 6;
    const int wm = wv >> 1;       // wave's m half (64)
    const int wn = wv & 1;        // wave's s half (64)

    f32x4 acc[4][4] = {};

    for (int k0 = 0; k0 < DIM; k0 += 64) {
        // stage tiles: 128 rows x 64 cols, f32 -> bf16
#pragma unroll
        for (int it = 0; it < 8; ++it) {
            int idx = it * 256 + t;          // 0..2047
            int row = idx >> 4;              // 0..127
            int c4  = (idx & 15) * 4;        // 0..60 step 4
            float4 w4 = *reinterpret_cast<const float4*>(&Wg[(size_t)(m0 + row) * DIM + k0 + c4]);
            ushort4 hw;
            hw.x = f2bf(w4.x); hw.y = f2bf(w4.y); hw.z = f2bf(w4.z); hw.w = f2bf(w4.w);
            *reinterpret_cast<ushort4*>(&Wt[row * LDP + c4]) = hw;
            float4 m4 = *reinterpret_cast<const float4*>(
                &Mg[((size_t)(s0 + row) * BATCH + b) * DIM + k0 + c4]);
            ushort4 hm;
            hm.x = f2bf(m4.x); hm.y = f2bf(m4.y); hm.z = f2bf(m4.z); hm.w = f2bf(m4.w);
            *reinterpret_cast<ushort4*>(&Mt[row * LDP + c4]) = hm;
        }
        __syncthreads();

#pragma unroll
        for (int kk = 0; kk < 64; kk += 32) {
            const int kb = kk + (lane >> 4) * 8;
            bf16x8 af[4], bf_[4];
#pragma unroll
            for (int i = 0; i < 4; ++i) {
                af[i]  = lds_frag(&Wt[(wm * 64 + i * 16 + (lane & 15)) * LDP + kb]);
                bf_[i] = lds_frag(&Mt[(wn * 64 + i * 16 + (lane & 15)) * LDP + kb]);
            }
#pragma unroll
            for (int i = 0; i < 4; ++i)
#pragma unroll
                for (int j = 0; j < 4; ++j)
                    acc[i][j] = __builtin_amdgcn_mfma_f32_16x16x32_bf16(af[i], bf_[j], acc[i][j], 0, 0, 0);
        }
        __syncthreads();
    }

    // epilogue: C[m][s] -> out[(b*512+m)*512 + s]
    const int scol = s0 + wn * 64 + (lane & 15);
#pragma unroll
    for (int i = 0; i < 4; ++i) {
#pragma unroll
        for (int r = 0; r < 4; ++r) {
            int m = m0 + wm * 64 + i * 16 + (lane >> 4) * 4 + r;
            size_t base = ((size_t)b * MAXLEN + m) * SEQ + scol;
#pragma unroll
            for (int j = 0; j < 4; ++j)
                out[base + j * 16] = acc[i][j][r];
        }
    }
}

// ---------------- softmax over s + edge mask/renorm, in place ----------------
// one wave per row (b*512+m); 4 rows per 256-thread block
__global__ __launch_bounds__(256) void softmax_mask(float* __restrict__ out,
                                                    const unsigned int* __restrict__ bits) {
    const int wv = threadIdx.x >> 6;
    const int lane = threadIdx.x & 63;
    const int row = blockIdx.x * 4 + wv;        // b*512 + m
    float* rp = out + (size_t)row * SEQ;
    const unsigned int* bw = bits + row * 16;

    float4 lo = reinterpret_cast<float4*>(rp)[lane];        // s = 4*lane .. +3
    float4 hi = reinterpret_cast<float4*>(rp)[lane + 64];   // s = 256 + 4*lane .. +3

    float mx = fmaxf(fmaxf(fmaxf(lo.x, lo.y), fmaxf(lo.z, lo.w)),
                     fmaxf(fmaxf(hi.x, hi.y), fmaxf(hi.z, hi.w)));
#pragma unroll
    for (int off = 32; off; off >>= 1) mx = fmaxf(mx, __shfl_xor(mx, off));

    float e[8];
    e[0] = __expf(lo.x - mx); e[1] = __expf(lo.y - mx);
    e[2] = __expf(lo.z - mx); e[3] = __expf(lo.w - mx);
    e[4] = __expf(hi.x - mx); e[5] = __expf(hi.y - mx);
    e[6] = __expf(hi.z - mx); e[7] = __expf(hi.w - mx);

    unsigned int wlo = bw[lane >> 3];
    unsigned int whi = bw[8 + (lane >> 3)];
    int sb = (lane * 4) & 31;

    float ed[8];
#pragma unroll
    for (int k = 0; k < 4; ++k) {
        ed[k]     = (float)((wlo >> (sb + k)) & 1u);
        ed[4 + k] = (float)((whi >> (sb + k)) & 1u);
    }

    float T = 0.f, Te = 0.f;
#pragma unroll
    for (int k = 0; k < 8; ++k) { T += e[k]; Te += e[k] * ed[k]; }
#pragma unroll
    for (int off = 32; off; off >>= 1) {
        T  += __shfl_xor(T, off);
        Te += __shfl_xor(Te, off);
    }

    float denom = Te + 1e-10f * (T - Te);
    float inv = 1.0f / denom;

    lo.x = ed[0] * e[0] * inv; lo.y = ed[1] * e[1] * inv;
    lo.z = ed[2] * e[2] * inv; lo.w = ed[3] * e[3] * inv;
    hi.x = ed[4] * e[4] * inv; hi.y = ed[5] * e[5] * inv;
    hi.z = ed[6] * e[6] * inv; hi.w = ed[7] * e[7] * inv;

    reinterpret_cast<float4*>(rp)[lane]      = lo;
    reinterpret_cast<float4*>(rp)[lane + 64] = hi;
}

extern "C" void kernel_launch(void* const* d_in, const int* in_sizes, int n_in,
                              void* d_out, int out_size, void* d_ws, size_t ws_size,
                              hipStream_t stream) {
    const float* Mg = (const float*)d_in[0];
    const float* Wg = (const float*)d_in[1];
    // d_in[2] = lengths (unused by reference)
    const int* eb = (const int*)d_in[3];
    const int* eu = (const int*)d_in[4];
    const int* ev = (const int*)d_in[5];
    const int E = in_sizes[3];

    float* out = (float*)d_out;
    unsigned int* bits = (unsigned int*)d_ws;   // 32768 rows * 16 words = 2 MB

    hipMemsetAsync(bits, 0, (size_t)BATCH * MAXLEN * 16 * sizeof(unsigned int), stream);
    edge_scatter<<<(E + 255) / 256, 256, 0, stream>>>(eb, eu, ev, bits, E);
    gemm_scale<<<dim3(4, 4, 64), 256, 0, stream>>>(Mg, Wg, out);
    softmax_mask<<<(BATCH * MAXLEN) / 4, 256, 0, stream>>>(out, bits);
}

// Round 2
// 92.701 us; speedup vs baseline: 1.0386x; 1.0386x over previous
//
#include <hip/hip_runtime.h>
#include <hip/hip_bf16.h>

// Shapes (fixed): SEQ=512, BATCH=64, DIM=512, MAXLEN=512, E=655360
// out[b][u][s] = edge(b,u,s) ? exp(scale-mx) / (T_e + 1e-10*(T-T_e)) : 0
// scale[s,b,m] = sum_d M[s,b,d] * W[m,d]
// Fused: one block computes m-tile(128) x full s(512) for one b, then does
// softmax + edge renorm in-register with small LDS cross-wave reductions.

#define SEQ 512
#define BATCH 64
#define DIM 512
#define MAXLEN 512
#define LDP 40   // LDS pitch (bf16 elems) for BK=32: 80B rows, 16B-aligned, 2-way bank alias (free)

typedef __attribute__((ext_vector_type(8))) __bf16 bf16x8;
typedef __attribute__((ext_vector_type(8))) unsigned short u16x8;
typedef __attribute__((ext_vector_type(4))) float f32x4;

__device__ __forceinline__ unsigned short f2bf(float f) {
    unsigned int u = __builtin_bit_cast(unsigned int, f);
    u += 0x7FFFu + ((u >> 16) & 1u);   // RNE
    return (unsigned short)(u >> 16);
}

__device__ __forceinline__ bf16x8 lds_frag(const unsigned short* p) {
    u16x8 r = *reinterpret_cast<const u16x8*>(p);
    return __builtin_bit_cast(bf16x8, r);
}

// ---------------- edge bitmap scatter ----------------
__global__ __launch_bounds__(256) void edge_scatter(const int* __restrict__ eb,
                                                    const int* __restrict__ eu,
                                                    const int* __restrict__ ev,
                                                    unsigned int* __restrict__ bits,
                                                    int E) {
    int i = blockIdx.x * 256 + threadIdx.x;
    if (i < E) {
        int b = eb[i], u = eu[i], v = ev[i];
        atomicOr(&bits[(b * MAXLEN + u) * 16 + (v >> 5)], 1u << (v & 31));
    }
}

// ---------------- fused GEMM + softmax + edge renorm ----------------
__global__ __launch_bounds__(512, 2) void fused_attn(const float* __restrict__ Mg,
                                                     const float* __restrict__ Wg,
                                                     const unsigned int* __restrict__ bitsG,
                                                     float* __restrict__ out) {
    __shared__ unsigned short Wt[128 * LDP];   // 10240 B; reused for reductions in epilogue
    __shared__ unsigned short Mt[512 * LDP];   // 40960 B
    __shared__ unsigned int   bitsL[128 * 20]; // 10240 B (pitch 20 words: 2-way on b128 reads)

    // XCD-concentrating work remap: blocks g with same g%8 (same XCD) handle
    // a contiguous chunk of b's -> M_b stays resident in one XCD's L2.
    const int g = blockIdx.x;
    const int work = (g & 7) * 32 + (g >> 3);   // bijective over [0,256)
    const int b  = work >> 2;
    const int m0 = (work & 3) * 128;

    const int t    = threadIdx.x;
    const int lane = t & 63;
    const int wv   = t >> 6;       // 0..7
    const int wm   = wv >> 2;      // m half (0..1) -> rows wm*64..+63
    const int ws   = wv & 3;       // s quarter (0..3) -> cols ws*128..+127
    const int lg   = lane >> 4;    // 0..3
    const int lc   = lane & 15;

    // stage edge bits for this block's 128 rows (one-time)
    {
        int row = t >> 2, wq = t & 3;
        uint4 w4 = *reinterpret_cast<const uint4*>(&bitsG[(size_t)(b * MAXLEN + m0 + row) * 16 + wq * 4]);
        *reinterpret_cast<uint4*>(&bitsL[row * 20 + wq * 4]) = w4;
    }

    f32x4 acc[4][8] = {};   // [m-frag i][s-frag j]

    for (int k0 = 0; k0 < DIM; k0 += 32) {
        // stage W tile 128x32 (2 float4 per thread)
#pragma unroll
        for (int it = 0; it < 2; ++it) {
            int id = it * 512 + t;
            int row = id >> 3, c4 = (id & 7) * 4;
            float4 v = *reinterpret_cast<const float4*>(&Wg[(size_t)(m0 + row) * DIM + k0 + c4]);
            ushort4 h;
            h.x = f2bf(v.x); h.y = f2bf(v.y); h.z = f2bf(v.z); h.w = f2bf(v.w);
            *reinterpret_cast<ushort4*>(&Wt[row * LDP + c4]) = h;
        }
        // stage M tile 512x32 (8 float4 per thread)
#pragma unroll
        for (int it = 0; it < 8; ++it) {
            int id = it * 512 + t;
            int row = id >> 3, c4 = (id & 7) * 4;   // row = s (0..511)
            float4 v = *reinterpret_cast<const float4*>(&Mg[((size_t)row * BATCH + b) * DIM + k0 + c4]);
            ushort4 h;
            h.x = f2bf(v.x); h.y = f2bf(v.y); h.z = f2bf(v.z); h.w = f2bf(v.w);
            *reinterpret_cast<ushort4*>(&Mt[row * LDP + c4]) = h;
        }
        __syncthreads();

        const int kb = lg * 8;
        bf16x8 af[4], bfr[8];
#pragma unroll
        for (int i = 0; i < 4; ++i)
            af[i] = lds_frag(&Wt[(wm * 64 + i * 16 + lc) * LDP + kb]);
#pragma unroll
        for (int j = 0; j < 8; ++j)
            bfr[j] = lds_frag(&Mt[(ws * 128 + j * 16 + lc) * LDP + kb]);
#pragma unroll
        for (int i = 0; i < 4; ++i)
#pragma unroll
            for (int j = 0; j < 8; ++j)
                acc[i][j] = __builtin_amdgcn_mfma_f32_16x16x32_bf16(af[i], bfr[j], acc[i][j], 0, 0, 0);
        __syncthreads();
    }

    // ---------------- epilogue: softmax over s + edge renorm ----------------
    // acc[i][j][r] = C[row = wm*64 + i*16 + lg*4 + r][col = ws*128 + j*16 + lc]
    float* rA = reinterpret_cast<float*>(Wt);    // [128][4] row-max partials per ws
    float2* rB = reinterpret_cast<float2*>(Wt);  // [128][4] (T, Te) partials per ws

    // Stage A: per-wave row max over its 128 cols -> LDS
#pragma unroll
    for (int i = 0; i < 4; ++i) {
#pragma unroll
        for (int r = 0; r < 4; ++r) {
            float v = acc[i][0][r];
#pragma unroll
            for (int j = 1; j < 8; ++j) v = fmaxf(v, acc[i][j][r]);
#pragma unroll
            for (int off = 1; off < 16; off <<= 1) v = fmaxf(v, __shfl_xor(v, off));
            if (lc == 0) rA[(wm * 64 + i * 16 + lg * 4 + r) * 4 + ws] = v;
        }
    }
    __syncthreads();

    // full row max (broadcast reads)
    float fullmax[4][4];
#pragma unroll
    for (int i = 0; i < 4; ++i)
#pragma unroll
        for (int r = 0; r < 4; ++r) {
            int m = wm * 64 + i * 16 + lg * 4 + r;
            float4 x = *reinterpret_cast<float4*>(&rA[m * 4]);
            fullmax[i][r] = fmaxf(fmaxf(x.x, x.y), fmaxf(x.z, x.w));
        }
    __syncthreads();   // before overwriting rA region with rB

    // Stage B: exp, T and Te partials -> LDS
#pragma unroll
    for (int i = 0; i < 4; ++i) {
#pragma unroll
        for (int r = 0; r < 4; ++r) {
            int m = wm * 64 + i * 16 + lg * 4 + r;
            uint4 w4 = *reinterpret_cast<uint4*>(&bitsL[m * 20 + ws * 4]);
            float T = 0.f, Te = 0.f;
#pragma unroll
            for (int j = 0; j < 8; ++j) {
                float e = __expf(acc[i][j][r] - fullmax[i][r]);
                acc[i][j][r] = e;
                unsigned int word = (j < 2) ? w4.x : (j < 4) ? w4.y : (j < 6) ? w4.z : w4.w;
                float bit = (float)((word >> ((j & 1) * 16 + lc)) & 1u);
                T += e;
                Te += e * bit;
            }
#pragma unroll
            for (int off = 1; off < 16; off <<= 1) {
                T  += __shfl_xor(T, off);
                Te += __shfl_xor(Te, off);
            }
            if (lc == 0) rB[m * 4 + ws] = make_float2(T, Te);
        }
    }
    __syncthreads();

    // final: inv denom per row, masked scaled writes
#pragma unroll
    for (int i = 0; i < 4; ++i) {
#pragma unroll
        for (int r = 0; r < 4; ++r) {
            int m = wm * 64 + i * 16 + lg * 4 + r;
            float T = 0.f, Te = 0.f;
#pragma unroll
            for (int q = 0; q < 4; ++q) {
                float2 p = rB[m * 4 + q];
                T += p.x; Te += p.y;
            }
            float inv = 1.0f / (Te + 1e-10f * (T - Te));
            uint4 w4 = *reinterpret_cast<uint4*>(&bitsL[m * 20 + ws * 4]);
            size_t base = ((size_t)(b * MAXLEN + m0 + m)) * SEQ + ws * 128 + lc;
#pragma unroll
            for (int j = 0; j < 8; ++j) {
                unsigned int word = (j < 2) ? w4.x : (j < 4) ? w4.y : (j < 6) ? w4.z : w4.w;
                unsigned int bit = (word >> ((j & 1) * 16 + lc)) & 1u;
                out[base + j * 16] = bit ? acc[i][j][r] * inv : 0.0f;
            }
        }
    }
}

extern "C" void kernel_launch(void* const* d_in, const int* in_sizes, int n_in,
                              void* d_out, int out_size, void* d_ws, size_t ws_size,
                              hipStream_t stream) {
    const float* Mg = (const float*)d_in[0];
    const float* Wg = (const float*)d_in[1];
    // d_in[2] = lengths (unused by reference)
    const int* eb = (const int*)d_in[3];
    const int* eu = (const int*)d_in[4];
    const int* ev = (const int*)d_in[5];
    const int E = in_sizes[3];

    float* out = (float*)d_out;
    unsigned int* bits = (unsigned int*)d_ws;   // 32768 rows * 16 words = 2 MB

    hipMemsetAsync(bits, 0, (size_t)BATCH * MAXLEN * 16 * sizeof(unsigned int), stream);
    edge_scatter<<<(E + 255) / 256, 256, 0, stream>>>(eb, eu, ev, bits, E);
    fused_attn<<<256, 512, 0, stream>>>(Mg, Wg, bits, out);
}